// Round 1
// 441.377 us; speedup vs baseline: 1.0452x; 1.0452x over previous
//
#include <hip/hip_runtime.h>
#include <hip/hip_bf16.h>
#include <math.h>

// Problem constants
#define NPIX 102400          // B*H*W
#define NSEED 4
#define RTOT (NPIX * NSEED)  // 409600 rows
#define GG 8
#define DD 64
#define EE 128
#define BM 64                // rows per block (16 pixels x 4 seeds)

// Padded K dims (multiples of 32 for 16x16x32 MFMA)
#define KP1 96               // 72 -> 96
#define KP2 128
#define KP3 160              // 159 -> 160

// Single union LDS buffer row stride (shorts). 168 shorts = 84 dw; lane
// stride 84 mod 32 = 20 -> 2-way bank aliasing on ds_read_b128 (free, m136).
// Phase A: cost k[0,96) + fourier k[128,160).  Phase B: h^T k[0,128) +
// fourier.  Phase C: F^T k[0,128) + fourier = stage-3 input k[0,160).
#define PS 168

typedef short bf16x8 __attribute__((ext_vector_type(8)));
typedef short bf16x4 __attribute__((ext_vector_type(4)));
typedef float f32x4 __attribute__((ext_vector_type(4)));

static __device__ __forceinline__ short f2bf(float x) {
    __hip_bfloat16 h = __float2bfloat16(x);  // RNE
    return __builtin_bit_cast(short, h);
}

// Fast gelu: Phi via Abramowitz-Stegun 7.1.26 erf (|err| < 1.5e-7), using
// hw v_rcp/v_exp. Error is ~1e-6*|x| -- far below the bf16 cast of h.
static __device__ __forceinline__ float gelu_fast(float x) {
    const float z = fabsf(x) * 0.7071067811865475f;
    const float t = __builtin_amdgcn_rcpf(__builtin_fmaf(0.3275911f, z, 1.0f));
    float p = __builtin_fmaf(1.061405429f, t, -1.453152027f);
    p = __builtin_fmaf(p, t, 1.421413741f);
    p = __builtin_fmaf(p, t, -0.284496736f);
    p = __builtin_fmaf(p, t, 0.254829592f);
    p = p * t;
    const float e = __expf(-z * z);          // native v_exp path
    const float q = 0.5f * p * e;            // Phi(-|x|)
    const float phi = (x >= 0.0f) ? (1.0f - q) : q;
    return x * phi;
}

// ---- pre-pass: transpose + bf16-cast weights, and build fourier LUT ----
// ws layout (shorts): W1T [128][96] @0 | W2T [128][128] @12288 |
//                     WpT [128][160] @28672 | Ftab [64][32] @49152
// total 51200 shorts = 100 KB
__global__ void prep_weights(const float* __restrict__ W1,
                             const float* __restrict__ W2,
                             const float* __restrict__ Wp,
                             short* __restrict__ ws) {
    const int i = blockIdx.x * 256 + threadIdx.x;  // grid covers 51200
    if (i < 12288) {
        const int e = i / KP1, k = i - e * KP1;
        ws[i] = (k < 72) ? f2bf(W1[k * EE + e]) : (short)0;
    } else if (i < 12288 + 16384) {
        const int j = i - 12288;
        const int e = j / KP2, k = j - e * KP2;
        ws[i] = f2bf(W2[k * EE + e]);
    } else if (i < 49152) {
        const int j = i - 28672;
        const int e = j / KP3, k = j - e * KP3;
        ws[i] = (k < 159) ? f2bf(Wp[k * EE + e]) : (short)0;
    } else if (i < 51200) {
        // fourier LUT: label values are integers 0..63 -> only 64 rows.
        // Same sinf/cosf as before, just hoisted out of the hot kernel.
        const int j = i - 49152;
        const int sd = j >> 5, c = j & 31;
        const float coord = (float)sd * (float)(3.14 / 64.0);
        float v;
        if (c < 15) v = sinf(coord * (float)(1 << c));
        else if (c < 30) v = cosf(coord * (float)(1 << (c - 15)));
        else if (c == 30) v = coord;
        else v = 0.0f;  // k=159 pad
        ws[i] = f2bf(v);
    }
}

// One K-stage of D^T = W^T(A) x act^T(B). Wave handles m-tiles {mt0,mt0+1} x n-tiles 0..3.
template <int KPAD, int PADB>
__device__ __forceinline__ void gemm_tiles(const short* __restrict__ WT, const short* sB,
                                           int mt0, int ln, int qd, f32x4 acc[2][4]) {
#pragma unroll
    for (int ks = 0; ks < KPAD / 32; ++ks) {
        const int kb = ks * 32 + qd * 8;
        const bf16x8 a0 = *(const bf16x8*)(WT + (mt0 * 16 + ln) * KPAD + kb);
        const bf16x8 a1 = *(const bf16x8*)(WT + (mt0 * 16 + 16 + ln) * KPAD + kb);
        const bf16x8 b0 = *(const bf16x8*)(sB + (0 * 16 + ln) * PADB + kb);
        const bf16x8 b1 = *(const bf16x8*)(sB + (1 * 16 + ln) * PADB + kb);
        const bf16x8 b2 = *(const bf16x8*)(sB + (2 * 16 + ln) * PADB + kb);
        const bf16x8 b3 = *(const bf16x8*)(sB + (3 * 16 + ln) * PADB + kb);
        acc[0][0] = __builtin_amdgcn_mfma_f32_16x16x32_bf16(a0, b0, acc[0][0], 0, 0, 0);
        acc[0][1] = __builtin_amdgcn_mfma_f32_16x16x32_bf16(a0, b1, acc[0][1], 0, 0, 0);
        acc[0][2] = __builtin_amdgcn_mfma_f32_16x16x32_bf16(a0, b2, acc[0][2], 0, 0, 0);
        acc[0][3] = __builtin_amdgcn_mfma_f32_16x16x32_bf16(a0, b3, acc[0][3], 0, 0, 0);
        acc[1][0] = __builtin_amdgcn_mfma_f32_16x16x32_bf16(a1, b0, acc[1][0], 0, 0, 0);
        acc[1][1] = __builtin_amdgcn_mfma_f32_16x16x32_bf16(a1, b1, acc[1][1], 0, 0, 0);
        acc[1][2] = __builtin_amdgcn_mfma_f32_16x16x32_bf16(a1, b2, acc[1][2], 0, 0, 0);
        acc[1][3] = __builtin_amdgcn_mfma_f32_16x16x32_bf16(a1, b3, acc[1][3], 0, 0, 0);
    }
}

// 7 blocks/CU: LDS 21760 B (floor(160K/21.8K)=7), VGPR cap 512/7=73 (was 52).
__global__ __launch_bounds__(256, 7)
void Propagation_85315230368231_kernel(const float* __restrict__ cost_volume,
                                       const int* __restrict__ label_seed,
                                       const short* __restrict__ ws,
                                       const float* __restrict__ b1,
                                       const float* __restrict__ b2,
                                       float* __restrict__ out) {
    __shared__ short sU[BM * PS];  // 21504 B, single union buffer
    __shared__ int sSeed[BM];

    const short* W1T = ws;
    const short* W2T = ws + 12288;
    const short* WpT = ws + 28672;
    const short* Ftab = ws + 49152;

    const int tid = threadIdx.x;
    const int blk = blockIdx.x;
    const int p0 = blk * (BM / NSEED);
    const int row0 = blk * BM;

    const int wave = tid >> 6;
    const int lane = tid & 63;
    const int ln = lane & 15;
    const int qd = lane >> 4;
    const int mt0 = wave * 2;

    if (tid < BM) {
        const int sd = label_seed[row0 + tid];
        sSeed[tid] = sd;
        out[(size_t)RTOT * EE + row0 + tid] = (float)sd;  // label_f output
    }
    __syncthreads();  // (1) seeds visible

    // ---- gather cost -> sU cols [0,72). One (row,group) pair per item:
    // base address + clamp amortized, 9 independent scattered loads in flight.
    {
        const int g = tid & 7;
#pragma unroll
        for (int i = 0; i < 2; ++i) {
            const int r = (tid >> 3) + i * 32;
            const int sd = sSeed[r];
            const float* cv = cost_volume + (size_t)(p0 + (r >> 2)) * (GG * DD) + g * DD;
            const int dbase = sd - 4;
            float v[9];
#pragma unroll
            for (int c = 0; c < 9; ++c) {
                int d = dbase + c;
                d = d < 0 ? 0 : d;
                d = d > 63 ? 63 : d;
                v[c] = cv[d];
            }
            short* dst = sU + r * PS + g * 9;
#pragma unroll
            for (int c = 0; c < 9; ++c) dst[c] = f2bf(v[c]);
        }
    }
    // zero-pad cols [72,96): 64 rows x 3 x 16B
    if (tid < 192) {
        const int r = tid / 3;
        const int j = tid - 3 * r;
        *(bf16x8*)(sU + r * PS + 72 + j * 8) = (bf16x8)0;
    }
    // fourier cols [128,160) from LUT: one 16B load + one 16B LDS write each
    {
        const int r = tid >> 2, ch = tid & 3;
        const bf16x8 t = *(const bf16x8*)(Ftab + sSeed[r] * 32 + ch * 8);
        *(bf16x8*)(sU + r * PS + 128 + ch * 8) = t;
    }
    __syncthreads();  // (2) cost + pad + fourier visible

    f32x4 acc[2][4];

    // ---- stage 1: h^T = gelu(W1T x cost^T + b1), acc in regs ----
#pragma unroll
    for (int i = 0; i < 2; ++i)
#pragma unroll
        for (int j = 0; j < 4; ++j) acc[i][j] = (f32x4)0.0f;
    gemm_tiles<KP1, PS>(W1T, sU, mt0, ln, qd, acc);
    __syncthreads();  // (3) all stage-1 sU reads done; safe to overwrite

#pragma unroll
    for (int mi = 0; mi < 2; ++mi) {
        const int eb = (mt0 + mi) * 16 + qd * 4;
        const float4 bv = *(const float4*)(b1 + eb);
#pragma unroll
        for (int nt = 0; nt < 4; ++nt) {
            bf16x4 p;
            p[0] = f2bf(gelu_fast(acc[mi][nt][0] + bv.x));
            p[1] = f2bf(gelu_fast(acc[mi][nt][1] + bv.y));
            p[2] = f2bf(gelu_fast(acc[mi][nt][2] + bv.z));
            p[3] = f2bf(gelu_fast(acc[mi][nt][3] + bv.w));
            *(bf16x4*)(sU + (nt * 16 + ln) * PS + eb) = p;
        }
    }
    __syncthreads();  // (4) h^T visible in sU cols [0,128)

    // ---- stage 2: F^T = W2T x h^T + b2, acc in regs ----
#pragma unroll
    for (int i = 0; i < 2; ++i)
#pragma unroll
        for (int j = 0; j < 4; ++j) acc[i][j] = (f32x4)0.0f;
    gemm_tiles<KP2, PS>(W2T, sU, mt0, ln, qd, acc);
    __syncthreads();  // (5) all stage-2 sU reads done; safe to overwrite

#pragma unroll
    for (int mi = 0; mi < 2; ++mi) {
        const int eb = (mt0 + mi) * 16 + qd * 4;
        const float4 bv = *(const float4*)(b2 + eb);
#pragma unroll
        for (int nt = 0; nt < 4; ++nt) {
            bf16x4 p;
            p[0] = f2bf(acc[mi][nt][0] + bv.x);
            p[1] = f2bf(acc[mi][nt][1] + bv.y);
            p[2] = f2bf(acc[mi][nt][2] + bv.z);
            p[3] = f2bf(acc[mi][nt][3] + bv.w);
            *(bf16x4*)(sU + (nt * 16 + ln) * PS + eb) = p;
        }
    }
    __syncthreads();  // (6) F^T visible; sU cols [0,160) = stage-3 input

    // ---- stage 3: out^T = WpT x [F|disp]^T ----
#pragma unroll
    for (int i = 0; i < 2; ++i)
#pragma unroll
        for (int j = 0; j < 4; ++j) acc[i][j] = (f32x4)0.0f;
    gemm_tiles<KP3, PS>(WpT, sU, mt0, ln, qd, acc);
#pragma unroll
    for (int mi = 0; mi < 2; ++mi) {
        const int eb = (mt0 + mi) * 16 + qd * 4;
#pragma unroll
        for (int nt = 0; nt < 4; ++nt) {
            const size_t grow = (size_t)(row0 + nt * 16 + ln);
            float4 v = {acc[mi][nt][0], acc[mi][nt][1], acc[mi][nt][2], acc[mi][nt][3]};
            *(float4*)(out + grow * EE + eb) = v;
        }
    }
}

extern "C" void kernel_launch(void* const* d_in, const int* in_sizes, int n_in,
                              void* d_out, int out_size, void* d_ws, size_t ws_size,
                              hipStream_t stream) {
    const float* cost_volume = (const float*)d_in[0];
    const int* label_seed = (const int*)d_in[1];
    // d_in[2] = context: unused (layers=[], norm=None)
    const float* W1 = (const float*)d_in[3];
    const float* b1 = (const float*)d_in[4];
    const float* W2 = (const float*)d_in[5];
    const float* b2 = (const float*)d_in[6];
    const float* Wp = (const float*)d_in[7];
    float* out = (float*)d_out;
    short* ws = (short*)d_ws;  // needs 51200 shorts = 100 KB

    prep_weights<<<200, 256, 0, stream>>>(W1, W2, Wp, ws);
    Propagation_85315230368231_kernel<<<RTOT / BM, 256, 0, stream>>>(
        cost_volume, label_seed, ws, b1, b2, out);
}